// Round 1
// baseline (4043.665 us; speedup 1.0000x reference)
//
#include <hip/hip_runtime.h>
#include <hip/hip_bf16.h>
#include <stdint.h>

#define DIMD 1024
#define NSEQ 4096
#define BATCH 8
#define BM 64
#define BN 32
#define LN_EPS 1e-5f

typedef __attribute__((ext_vector_type(8))) short bf16x8;
typedef __attribute__((ext_vector_type(4))) float f32x4;

// ---- attention kernel LDS layout (bytes) ----
#define KRM_OFF   0        // [32][2048B] K tile, row-major, XOR-swizzled
#define VT_OFF    65536    // [1024][80B] V^T tile (32 n + 8 pad) bf16
#define SBUF_OFF  147456   // [64][32] f32 score buffer
#define PBUF_OFF  155648   // [64][80B] P bf16, padded rows
#define RMAX_OFF  160768   // [64] f32 running max
#define RSUM_OFF  161024   // [64] f32 running sum
#define CORR_OFF  161280   // [64] f32 per-iter correction
#define LDS_TOTAL 161536

__device__ __forceinline__ ushort f2bf(float f) {
  union { __hip_bfloat16 h; ushort u; } cv;
  cv.h = __float2bfloat16(f);
  return cv.u;
}

__device__ __forceinline__ void gload16(const void* g, void* l) {
  __builtin_amdgcn_global_load_lds(
      (const __attribute__((address_space(1))) uint32_t*)g,
      (__attribute__((address_space(3))) uint32_t*)l, 16, 0, 0);
}

// ---------------- LayerNorm (fp32 in -> bf16 out, scale folded) -------------
// one wave per row, 4 rows per 256-thread block
__global__ __launch_bounds__(256) void ln_bf16_kernel(
    const float* __restrict__ x, const float* __restrict__ gamma,
    const float* __restrict__ beta, ushort* __restrict__ y, float scale)
{
  const int lane = threadIdx.x & 63;
  const int wv   = threadIdx.x >> 6;
  const size_t row = (size_t)blockIdx.x * 4 + wv;
  const float* xr = x + row * DIMD;

  float4 v[4];
#pragma unroll
  for (int c = 0; c < 4; ++c)
    v[c] = *(const float4*)(xr + c * 256 + lane * 4);

  float s = 0.f;
#pragma unroll
  for (int c = 0; c < 4; ++c) s += v[c].x + v[c].y + v[c].z + v[c].w;
#pragma unroll
  for (int m = 32; m >= 1; m >>= 1) s += __shfl_xor(s, m, 64);
  const float mean = s * (1.0f / DIMD);

  float vs = 0.f;
#pragma unroll
  for (int c = 0; c < 4; ++c) {
    float a0 = v[c].x - mean, a1 = v[c].y - mean;
    float a2 = v[c].z - mean, a3 = v[c].w - mean;
    vs += a0 * a0 + a1 * a1 + a2 * a2 + a3 * a3;
  }
#pragma unroll
  for (int m = 32; m >= 1; m >>= 1) vs += __shfl_xor(vs, m, 64);
  const float rstd = rsqrtf(vs * (1.0f / DIMD) + LN_EPS);

  ushort* yr = y + row * DIMD;
#pragma unroll
  for (int c = 0; c < 4; ++c) {
    const int d = c * 256 + lane * 4;
    float4 g  = *(const float4*)(gamma + d);
    float4 bb = *(const float4*)(beta + d);
    ushort4 o;
    o.x = f2bf(((v[c].x - mean) * rstd * g.x + bb.x) * scale);
    o.y = f2bf(((v[c].y - mean) * rstd * g.y + bb.y) * scale);
    o.z = f2bf(((v[c].z - mean) * rstd * g.z + bb.z) * scale);
    o.w = f2bf(((v[c].w - mean) * rstd * g.w + bb.w) * scale);
    *(ushort4*)(yr + d) = o;
  }
}

// ---------------- bf16 transpose: [b][n][d] -> [b][d][n] --------------------
__global__ __launch_bounds__(256) void transpose_kernel(
    const ushort* __restrict__ src, ushort* __restrict__ dst)
{
  __shared__ ushort tile[64][72];
  const int t   = threadIdx.x;
  const int bid = blockIdx.x;
  const int b   = bid >> 10;
  const int rem = bid & 1023;
  const int n0  = (rem >> 4) << 6;
  const int d0  = (rem & 15) << 6;
  const ushort* sb = src + ((size_t)b * NSEQ) * DIMD;
  ushort* db       = dst + ((size_t)b * DIMD) * NSEQ;

#pragma unroll
  for (int k = 0; k < 2; ++k) {
    int c = t + 256 * k;
    int r = c >> 3, scol = (c & 7) * 8;
    *(uint4*)&tile[r][scol] =
        *(const uint4*)(sb + (size_t)(n0 + r) * DIMD + d0 + scol);
  }
  __syncthreads();
#pragma unroll
  for (int k = 0; k < 2; ++k) {
    int c = t + 256 * k;
    int dr = c >> 3, ns = (c & 7) * 8;
    union { ushort u[8]; uint4 q; } tv;
#pragma unroll
    for (int i = 0; i < 8; ++i) tv.u[i] = tile[ns + i][dr];
    *(uint4*)(db + (size_t)(d0 + dr) * NSEQ + n0 + ns) = tv.q;
  }
}

// ---------------- fused flash attention -------------------------------------
// 512 threads = 8 waves: wave = (wm in 0..1) * 4 + (wd in 0..3)
// block computes out[q0 .. q0+64) x [0..1024) for batch b
__global__ __launch_bounds__(512, 2) void attn_kernel(
    const ushort* __restrict__ Qb, const ushort* __restrict__ Kb,
    const ushort* __restrict__ Ktb, float* __restrict__ Out)
{
  extern __shared__ char smem[];
  const int tid  = threadIdx.x;
  const int lane = tid & 63;
  const int wave = tid >> 6;
  const int wm   = wave >> 2;   // 0..1 : q-row half
  const int wd   = wave & 3;    // 0..3 : 256-wide d-slice
  const int l15  = lane & 15;
  const int lg   = lane >> 4;   // 0..3

  const int b  = blockIdx.x & 7;
  const int q0 = (blockIdx.x >> 3) * BM;

  const ushort* Qbase  = Qb  + ((size_t)b * NSEQ + q0) * DIMD;
  const ushort* Kbase  = Kb  + (size_t)b * NSEQ * DIMD;
  const ushort* Ktbase = Ktb + (size_t)b * DIMD * NSEQ;

  float* Sb = (float*)(smem + SBUF_OFF);
  float* RM = (float*)(smem + RMAX_OFF);
  float* RS = (float*)(smem + RSUM_OFF);
  float* CR = (float*)(smem + CORR_OFF);

  // Q fragments in registers: rows wm*32+mt*16+l15, d = wd*256+ks*32+lg*8
  bf16x8 qf[2][8];
#pragma unroll
  for (int mt = 0; mt < 2; ++mt)
#pragma unroll
    for (int ks = 0; ks < 8; ++ks) {
      int r = wm * 32 + mt * 16 + l15;
      int d = wd * 256 + ks * 32 + lg * 8;
      qf[mt][ks] = *(const bf16x8*)(Qbase + (size_t)r * DIMD + d);
    }

  f32x4 acc[2][16];
#pragma unroll
  for (int mt = 0; mt < 2; ++mt)
#pragma unroll
    for (int dt = 0; dt < 16; ++dt) acc[mt][dt] = 0.0f;

  if (tid < 64) { RM[tid] = -1e30f; RS[tid] = 0.f; }

  // staging source element-offsets (fixed per thread; add n0-dependent base per iter)
  int krm_src[8];
#pragma unroll
  for (int k = 0; k < 8; ++k) {
    int o = (tid + 512 * k) * 16;          // LDS byte offset in K tile
    int n = o >> 11;
    int x = o & 2047;
    int d = (x ^ ((n & 15) << 4)) >> 1;    // inverse of read-side XOR swizzle
    krm_src[k] = n * DIMD + d;
  }
  int vt_src[10];
#pragma unroll
  for (int k = 0; k < 10; ++k) {
    int o = (tid + 512 * k) * 16;          // LDS byte offset in Vt tile
    int d = o / 80;
    int srem = o - d * 80;
    vt_src[k] = d * NSEQ + (srem == 64 ? 0 : (srem >> 1)); // srem==64 -> pad slot
  }

  for (int it = 0; it < NSEQ / BN; ++it) {
    const int n0 = it * BN;
    __syncthreads();  // B0: prev PV reads of K/Vt/Pbuf done

    const ushort* krow = Kbase + (size_t)n0 * DIMD;
#pragma unroll
    for (int k = 0; k < 8; ++k)
      gload16(krow + krm_src[k], smem + KRM_OFF + (tid + 512 * k) * 16);
    const ushort* ktrow = Ktbase + n0;
#pragma unroll
    for (int k = 0; k < 10; ++k)
      gload16(ktrow + vt_src[k], smem + VT_OFF + (tid + 512 * k) * 16);
#pragma unroll
    for (int j = 0; j < 4; ++j) Sb[tid + 512 * j] = 0.f;
    __syncthreads();  // B1: staging + zero visible

    // ---- QK^T partial over this wave's 256-wide d-slice ----
    f32x4 sacc[2][2];
#pragma unroll
    for (int mt = 0; mt < 2; ++mt)
#pragma unroll
      for (int nt = 0; nt < 2; ++nt) sacc[mt][nt] = 0.0f;

#pragma unroll
    for (int ks = 0; ks < 8; ++ks) {
      bf16x8 kf[2];
#pragma unroll
      for (int nt = 0; nt < 2; ++nt) {
        int n = nt * 16 + l15;
        int d = wd * 256 + ks * 32 + lg * 8;
        int off = n * 2048 + ((d * 2) ^ ((n & 15) << 4));
        kf[nt] = *(const bf16x8*)(smem + KRM_OFF + off);
      }
#pragma unroll
      for (int mt = 0; mt < 2; ++mt)
#pragma unroll
        for (int nt = 0; nt < 2; ++nt)
          sacc[mt][nt] = __builtin_amdgcn_mfma_f32_16x16x32_bf16(
              qf[mt][ks], kf[nt], sacc[mt][nt], 0, 0, 0);
    }
    // reduce partials across the 4 d-waves
#pragma unroll
    for (int mt = 0; mt < 2; ++mt)
#pragma unroll
      for (int nt = 0; nt < 2; ++nt)
#pragma unroll
        for (int i = 0; i < 4; ++i) {
          int r  = wm * 32 + mt * 16 + lg * 4 + i;
          int cc = nt * 16 + l15;
          atomicAdd(Sb + r * 32 + cc, sacc[mt][nt][i]);
        }
    __syncthreads();  // B2: S complete

    // ---- online softmax: 8 threads per row, 4 cols each ----
    {
      const int row = tid >> 3;
      const int c0  = (tid & 7) * 4;
      float s0 = Sb[row * 32 + c0 + 0];
      float s1 = Sb[row * 32 + c0 + 1];
      float s2 = Sb[row * 32 + c0 + 2];
      float s3 = Sb[row * 32 + c0 + 3];
      float mx = fmaxf(fmaxf(s0, s1), fmaxf(s2, s3));
#pragma unroll
      for (int m = 1; m < 8; m <<= 1) mx = fmaxf(mx, __shfl_xor(mx, m, 8));
      const float Mold = RM[row];
      const float Mnew = fmaxf(Mold, mx);
      const float p0 = __expf(s0 - Mnew);
      const float p1 = __expf(s1 - Mnew);
      const float p2 = __expf(s2 - Mnew);
      const float p3 = __expf(s3 - Mnew);
      float ps = p0 + p1 + p2 + p3;
#pragma unroll
      for (int m = 1; m < 8; m <<= 1) ps += __shfl_xor(ps, m, 8);
      const float cfac = __expf(Mold - Mnew);
      if ((tid & 7) == 0) {
        RM[row] = Mnew;
        RS[row] = RS[row] * cfac + ps;
        CR[row] = cfac;
      }
      ushort4 pw;
      pw.x = f2bf(p0); pw.y = f2bf(p1); pw.z = f2bf(p2); pw.w = f2bf(p3);
      *(ushort4*)(smem + PBUF_OFF + row * 80 + c0 * 2) = pw;
    }
    __syncthreads();  // B3: P + stats visible

    // ---- rescale accumulator, then PV ----
    float cr[2][4];
#pragma unroll
    for (int mt = 0; mt < 2; ++mt)
#pragma unroll
      for (int i = 0; i < 4; ++i)
        cr[mt][i] = CR[wm * 32 + mt * 16 + lg * 4 + i];
#pragma unroll
    for (int mt = 0; mt < 2; ++mt)
#pragma unroll
      for (int dt = 0; dt < 16; ++dt)
#pragma unroll
        for (int i = 0; i < 4; ++i) acc[mt][dt][i] *= cr[mt][i];

    bf16x8 pf[2];
#pragma unroll
    for (int mt = 0; mt < 2; ++mt) {
      int r = wm * 32 + mt * 16 + l15;
      pf[mt] = *(const bf16x8*)(smem + PBUF_OFF + r * 80 + lg * 16);
    }
#pragma unroll
    for (int dt = 0; dt < 16; ++dt) {
      int d = wd * 256 + dt * 16 + l15;
      bf16x8 vf = *(const bf16x8*)(smem + VT_OFF + d * 80 + lg * 16);
#pragma unroll
      for (int mt = 0; mt < 2; ++mt)
        acc[mt][dt] = __builtin_amdgcn_mfma_f32_16x16x32_bf16(
            pf[mt], vf, acc[mt][dt], 0, 0, 0);
    }
  }

  // ---- epilogue: divide by running sum, write fp32 out ----
  float inv[2][4];
#pragma unroll
  for (int mt = 0; mt < 2; ++mt)
#pragma unroll
    for (int i = 0; i < 4; ++i)
      inv[mt][i] = 1.0f / RS[wm * 32 + mt * 16 + lg * 4 + i];
#pragma unroll
  for (int mt = 0; mt < 2; ++mt)
#pragma unroll
    for (int dt = 0; dt < 16; ++dt) {
      int d = wd * 256 + dt * 16 + l15;
#pragma unroll
      for (int i = 0; i < 4; ++i) {
        int r = q0 + wm * 32 + mt * 16 + lg * 4 + i;
        Out[((size_t)b * NSEQ + r) * DIMD + d] = acc[mt][dt][i] * inv[mt][i];
      }
    }
}

extern "C" void kernel_launch(void* const* d_in, const int* in_sizes, int n_in,
                              void* d_out, int out_size, void* d_ws, size_t ws_size,
                              hipStream_t stream) {
  const float* vis = (const float*)d_in[0];
  const float* txt = (const float*)d_in[1];
  const float* gv  = (const float*)d_in[2];
  const float* bv  = (const float*)d_in[3];
  const float* gt  = (const float*)d_in[4];
  const float* bt  = (const float*)d_in[5];
  float* out = (float*)d_out;

  const size_t tokens = (size_t)BATCH * NSEQ * DIMD;  // 33,554,432 elements
  ushort* Qbf = (ushort*)d_ws;          // LN(visual)/32, bf16, 64 MiB
  ushort* Kbf = Qbf + tokens;           // LN(text), bf16, 64 MiB
  ushort* Ktb = Kbf + tokens;           // LN(text)^T, bf16, 64 MiB

  // scale 1/sqrt(1024) folded into visual LN output
  ln_bf16_kernel<<<BATCH * NSEQ / 4, 256, 0, stream>>>(vis, gv, bv, Qbf, 0.03125f);
  ln_bf16_kernel<<<BATCH * NSEQ / 4, 256, 0, stream>>>(txt, gt, bt, Kbf, 1.0f);
  transpose_kernel<<<BATCH * (NSEQ / 64) * (DIMD / 64), 256, 0, stream>>>(Kbf, Ktb);

  hipFuncSetAttribute((const void*)attn_kernel,
                      hipFuncAttributeMaxDynamicSharedMemorySize, LDS_TOTAL);
  attn_kernel<<<BATCH * (NSEQ / BM), 512, LDS_TOTAL, stream>>>(Qbf, Kbf, Ktb, out);
}

// Round 2
// 994.349 us; speedup vs baseline: 4.0666x; 4.0666x over previous
//
#include <hip/hip_runtime.h>
#include <hip/hip_bf16.h>
#include <stdint.h>

#define DIMD 1024
#define NSEQ 4096
#define BATCH 8
#define BM 64
#define BN 32
#define LN_EPS 1e-5f

typedef __attribute__((ext_vector_type(8))) short bf16x8;
typedef __attribute__((ext_vector_type(4))) float f32x4;

// ---- flash-attn fallback LDS layout (bytes) ----
#define KRM_OFF   0
#define VT_OFF    65536
#define SBUF_OFF  147456
#define PBUF_OFF  155648
#define RMAX_OFF  160768
#define RSUM_OFF  161024
#define CORR_OFF  161280
#define LDS_TOTAL 161536

__device__ __forceinline__ ushort f2bf(float f) {
  union { __hip_bfloat16 h; ushort u; } cv;
  cv.h = __float2bfloat16(f);
  return cv.u;
}

__device__ __forceinline__ void gload16(const void* g, void* l) {
  __builtin_amdgcn_global_load_lds(
      (const __attribute__((address_space(1))) uint32_t*)g,
      (__attribute__((address_space(3))) uint32_t*)l, 16, 0, 0);
}

// ---------------- LayerNorm (fp32 in -> bf16 out, scale folded) -------------
__global__ __launch_bounds__(256) void ln_bf16_kernel(
    const float* __restrict__ x, const float* __restrict__ gamma,
    const float* __restrict__ beta, ushort* __restrict__ y, float scale)
{
  const int lane = threadIdx.x & 63;
  const int wv   = threadIdx.x >> 6;
  const size_t row = (size_t)blockIdx.x * 4 + wv;
  const float* xr = x + row * DIMD;

  float4 v[4];
#pragma unroll
  for (int c = 0; c < 4; ++c)
    v[c] = *(const float4*)(xr + c * 256 + lane * 4);

  float s = 0.f;
#pragma unroll
  for (int c = 0; c < 4; ++c) s += v[c].x + v[c].y + v[c].z + v[c].w;
#pragma unroll
  for (int m = 32; m >= 1; m >>= 1) s += __shfl_xor(s, m, 64);
  const float mean = s * (1.0f / DIMD);

  float vs = 0.f;
#pragma unroll
  for (int c = 0; c < 4; ++c) {
    float a0 = v[c].x - mean, a1 = v[c].y - mean;
    float a2 = v[c].z - mean, a3 = v[c].w - mean;
    vs += a0 * a0 + a1 * a1 + a2 * a2 + a3 * a3;
  }
#pragma unroll
  for (int m = 32; m >= 1; m >>= 1) vs += __shfl_xor(vs, m, 64);
  const float rstd = rsqrtf(vs * (1.0f / DIMD) + LN_EPS);

  ushort* yr = y + row * DIMD;
#pragma unroll
  for (int c = 0; c < 4; ++c) {
    const int d = c * 256 + lane * 4;
    float4 g  = *(const float4*)(gamma + d);
    float4 bb = *(const float4*)(beta + d);
    ushort4 o;
    o.x = f2bf(((v[c].x - mean) * rstd * g.x + bb.x) * scale);
    o.y = f2bf(((v[c].y - mean) * rstd * g.y + bb.y) * scale);
    o.z = f2bf(((v[c].z - mean) * rstd * g.z + bb.z) * scale);
    o.w = f2bf(((v[c].w - mean) * rstd * g.w + bb.w) * scale);
    *(ushort4*)(yr + d) = o;
  }
}

// ---------------- bf16 transpose: [b][n][d] -> [b][d][n] --------------------
__global__ __launch_bounds__(256) void transpose_kernel(
    const ushort* __restrict__ src, ushort* __restrict__ dst)
{
  __shared__ ushort tile[64][72];
  const int t   = threadIdx.x;
  const int bid = blockIdx.x;
  const int b   = bid >> 10;
  const int rem = bid & 1023;
  const int n0  = (rem >> 4) << 6;
  const int d0  = (rem & 15) << 6;
  const ushort* sb = src + ((size_t)b * NSEQ) * DIMD;
  ushort* db       = dst + ((size_t)b * DIMD) * NSEQ;

#pragma unroll
  for (int k = 0; k < 2; ++k) {
    int c = t + 256 * k;
    int r = c >> 3, scol = (c & 7) * 8;
    *(uint4*)&tile[r][scol] =
        *(const uint4*)(sb + (size_t)(n0 + r) * DIMD + d0 + scol);
  }
  __syncthreads();
#pragma unroll
  for (int k = 0; k < 2; ++k) {
    int c = t + 256 * k;
    int dr = c >> 3, ns = (c & 7) * 8;
    union { ushort u[8]; uint4 q; } tv;
#pragma unroll
    for (int i = 0; i < 8; ++i) tv.u[i] = tile[ns + i][dr];
    *(uint4*)(db + (size_t)(d0 + dr) * NSEQ + n0 + ns) = tv.q;
  }
}

// ================== two-pass GEMM path ======================================
// GEMM1: S = exp(Q . K^T), S bf16 [4096][4096]; row-sums into Rsum (atomics).
// m97-style 128x128 tile, BK=64, 4 waves, global_load_lds w=16, linear LDS.
__global__ __launch_bounds__(256) void gemm1_kernel(
    const ushort* __restrict__ Q, const ushort* __restrict__ K,
    ushort* __restrict__ S, float* __restrict__ Rsum,
    int b0, size_t s_stride)
{
  __shared__ ushort At[128 * 64];
  __shared__ ushort Bt[128 * 64];
  const int tid  = threadIdx.x;
  const int lane = tid & 63;
  const int wave = tid >> 6;
  const int wr = wave >> 1, wc = wave & 1;
  const int l15 = lane & 15, lg = lane >> 4;

  // XCD-aware bijective swizzle (total blocks divisible by 8)
  const int lid = blockIdx.x + (blockIdx.y << 5) + (blockIdx.z << 10);
  const int total = (int)(gridDim.x * gridDim.y * gridDim.z);
  const int swz = (lid & 7) * (total >> 3) + (lid >> 3);
  const int bx = swz & 31, by = (swz >> 5) & 31, bzc = swz >> 10;

  const int bz   = b0 + bzc;
  const int row0 = by * 128, col0 = bx * 128;
  const ushort* Ab = Q + (size_t)bz * NSEQ * DIMD + (size_t)row0 * DIMD;
  const ushort* Bb = K + (size_t)bz * NSEQ * DIMD + (size_t)col0 * DIMD;

  f32x4 acc[4][4];
#pragma unroll
  for (int ai = 0; ai < 4; ++ai)
#pragma unroll
    for (int bj = 0; bj < 4; ++bj) acc[ai][bj] = 0.0f;

  const int srow  = tid >> 3;          // staging row (0..31), +32 per sub-load
  const int skoff = (tid & 7) * 8;     // staging k-offset (elements)

  for (int ks = 0; ks < DIMD / 64; ++ks) {
    __syncthreads();
#pragma unroll
    for (int l = 0; l < 4; ++l)
      gload16(Ab + (size_t)(srow + 32 * l) * DIMD + ks * 64 + skoff,
              At + (tid + 256 * l) * 8);
#pragma unroll
    for (int l = 0; l < 4; ++l)
      gload16(Bb + (size_t)(srow + 32 * l) * DIMD + ks * 64 + skoff,
              Bt + (tid + 256 * l) * 8);
    __syncthreads();
#pragma unroll
    for (int kk = 0; kk < 2; ++kk) {
      bf16x8 af[4], bfr[4];
#pragma unroll
      for (int ai = 0; ai < 4; ++ai)
        af[ai] = *(const bf16x8*)(At + (wr * 64 + ai * 16 + l15) * 64 + kk * 32 + lg * 8);
#pragma unroll
      for (int bj = 0; bj < 4; ++bj)
        bfr[bj] = *(const bf16x8*)(Bt + (wc * 64 + bj * 16 + l15) * 64 + kk * 32 + lg * 8);
#pragma unroll
      for (int ai = 0; ai < 4; ++ai)
#pragma unroll
        for (int bj = 0; bj < 4; ++bj)
          acc[ai][bj] = __builtin_amdgcn_mfma_f32_16x16x32_bf16(
              af[ai], bfr[bj], acc[ai][bj], 0, 0, 0);
    }
  }

  // epilogue: p = exp(s) (no max subtraction; |s|<=32 so f32-safe),
  // store bf16 S, row-sum via 16-lane shuffle reduce + global f32 atomics.
  ushort* Sb = S + (size_t)bzc * s_stride;
  float*  Rs = Rsum + (size_t)bz * NSEQ;
#pragma unroll
  for (int ai = 0; ai < 4; ++ai) {
    float rsum[4] = {0.f, 0.f, 0.f, 0.f};
#pragma unroll
    for (int bj = 0; bj < 4; ++bj) {
      const int c = col0 + wc * 64 + bj * 16 + l15;
#pragma unroll
      for (int i = 0; i < 4; ++i) {
        const int r = row0 + wr * 64 + ai * 16 + lg * 4 + i;
        float p = __expf(acc[ai][bj][i]);
        Sb[(size_t)r * NSEQ + c] = f2bf(p);
        rsum[i] += p;
      }
    }
#pragma unroll
    for (int i = 0; i < 4; ++i) {
      float v = rsum[i];
      v += __shfl_xor(v, 1, 64);
      v += __shfl_xor(v, 2, 64);
      v += __shfl_xor(v, 4, 64);
      v += __shfl_xor(v, 8, 64);
      if (l15 == 0)
        atomicAdd(Rs + row0 + wr * 64 + ai * 16 + lg * 4 + i, v);
    }
  }
}

// GEMM2: O = (S . V) / Rsum,  A = S bf16 [4096][4096], B = V^T (=Kt) [1024][4096]
__global__ __launch_bounds__(256) void gemm2_kernel(
    const ushort* __restrict__ S, const ushort* __restrict__ Kt,
    const float* __restrict__ Rsum, float* __restrict__ Out,
    int b0, size_t s_stride)
{
  __shared__ ushort At[128 * 64];
  __shared__ ushort Bt[128 * 64];
  const int tid  = threadIdx.x;
  const int lane = tid & 63;
  const int wave = tid >> 6;
  const int wr = wave >> 1, wc = wave & 1;
  const int l15 = lane & 15, lg = lane >> 4;

  const int lid = blockIdx.x + (blockIdx.y << 3) + (blockIdx.z << 8);
  const int total = (int)(gridDim.x * gridDim.y * gridDim.z);
  const int swz = (lid & 7) * (total >> 3) + (lid >> 3);
  const int bx = swz & 7, by = (swz >> 3) & 31, bzc = swz >> 8;

  const int bz   = b0 + bzc;
  const int row0 = by * 128;   // v rows
  const int col0 = bx * 128;   // d cols
  const ushort* Ab = S  + (size_t)bzc * s_stride + (size_t)row0 * NSEQ;
  const ushort* Bb = Kt + (size_t)bz * DIMD * NSEQ + (size_t)col0 * NSEQ;

  f32x4 acc[4][4];
#pragma unroll
  for (int ai = 0; ai < 4; ++ai)
#pragma unroll
    for (int bj = 0; bj < 4; ++bj) acc[ai][bj] = 0.0f;

  const int srow  = tid >> 3;
  const int skoff = (tid & 7) * 8;

  for (int ks = 0; ks < NSEQ / 64; ++ks) {
    __syncthreads();
#pragma unroll
    for (int l = 0; l < 4; ++l)
      gload16(Ab + (size_t)(srow + 32 * l) * NSEQ + ks * 64 + skoff,
              At + (tid + 256 * l) * 8);
#pragma unroll
    for (int l = 0; l < 4; ++l)
      gload16(Bb + (size_t)(srow + 32 * l) * NSEQ + ks * 64 + skoff,
              Bt + (tid + 256 * l) * 8);
    __syncthreads();
#pragma unroll
    for (int kk = 0; kk < 2; ++kk) {
      bf16x8 af[4], bfr[4];
#pragma unroll
      for (int ai = 0; ai < 4; ++ai)
        af[ai] = *(const bf16x8*)(At + (wr * 64 + ai * 16 + l15) * 64 + kk * 32 + lg * 8);
#pragma unroll
      for (int bj = 0; bj < 4; ++bj)
        bfr[bj] = *(const bf16x8*)(Bt + (wc * 64 + bj * 16 + l15) * 64 + kk * 32 + lg * 8);
#pragma unroll
      for (int ai = 0; ai < 4; ++ai)
#pragma unroll
        for (int bj = 0; bj < 4; ++bj)
          acc[ai][bj] = __builtin_amdgcn_mfma_f32_16x16x32_bf16(
              af[ai], bfr[bj], acc[ai][bj], 0, 0, 0);
    }
  }

  const float* Rs = Rsum + (size_t)bz * NSEQ;
  float* Ob = Out + (size_t)bz * NSEQ * DIMD;
#pragma unroll
  for (int ai = 0; ai < 4; ++ai) {
#pragma unroll
    for (int i = 0; i < 4; ++i) {
      const int r = row0 + wr * 64 + ai * 16 + lg * 4 + i;
      const float inv = 1.0f / Rs[r];
#pragma unroll
      for (int bj = 0; bj < 4; ++bj) {
        const int c = col0 + wc * 64 + bj * 16 + l15;
        Ob[(size_t)r * DIMD + c] = acc[ai][bj][i] * inv;
      }
    }
  }
}

// ================== flash-attn fallback (round-1, known-passing) ============
__global__ __launch_bounds__(512, 2) void attn_kernel(
    const ushort* __restrict__ Qb, const ushort* __restrict__ Kb,
    const ushort* __restrict__ Ktb, float* __restrict__ Out)
{
  extern __shared__ char smem[];
  const int tid  = threadIdx.x;
  const int lane = tid & 63;
  const int wave = tid >> 6;
  const int wm   = wave >> 2;
  const int wd   = wave & 3;
  const int l15  = lane & 15;
  const int lg   = lane >> 4;

  const int b  = blockIdx.x & 7;
  const int q0 = (blockIdx.x >> 3) * BM;

  const ushort* Qbase  = Qb  + ((size_t)b * NSEQ + q0) * DIMD;
  const ushort* Kbase  = Kb  + (size_t)b * NSEQ * DIMD;
  const ushort* Ktbase = Ktb + (size_t)b * DIMD * NSEQ;

  float* Sb = (float*)(smem + SBUF_OFF);
  float* RM = (float*)(smem + RMAX_OFF);
  float* RS = (float*)(smem + RSUM_OFF);
  float* CR = (float*)(smem + CORR_OFF);

  bf16x8 qf[2][8];
#pragma unroll
  for (int mt = 0; mt < 2; ++mt)
#pragma unroll
    for (int ks = 0; ks < 8; ++ks) {
      int r = wm * 32 + mt * 16 + l15;
      int d = wd * 256 + ks * 32 + lg * 8;
      qf[mt][ks] = *(const bf16x8*)(Qbase + (size_t)r * DIMD + d);
    }

  f32x4 acc[2][16];
#pragma unroll
  for (int mt = 0; mt < 2; ++mt)
#pragma unroll
    for (int dt = 0; dt < 16; ++dt) acc[mt][dt] = 0.0f;

  if (tid < 64) { RM[tid] = -1e30f; RS[tid] = 0.f; }

  int krm_src[8];
#pragma unroll
  for (int k = 0; k < 8; ++k) {
    int o = (tid + 512 * k) * 16;
    int n = o >> 11;
    int x = o & 2047;
    int d = (x ^ ((n & 15) << 4)) >> 1;
    krm_src[k] = n * DIMD + d;
  }
  int vt_src[10];
#pragma unroll
  for (int k = 0; k < 10; ++k) {
    int o = (tid + 512 * k) * 16;
    int d = o / 80;
    int srem = o - d * 80;
    vt_src[k] = d * NSEQ + (srem == 64 ? 0 : (srem >> 1));
  }

  for (int it = 0; it < NSEQ / BN; ++it) {
    const int n0 = it * BN;
    __syncthreads();

    const ushort* krow = Kbase + (size_t)n0 * DIMD;
#pragma unroll
    for (int k = 0; k < 8; ++k)
      gload16(krow + krm_src[k], smem + KRM_OFF + (tid + 512 * k) * 16);
    const ushort* ktrow = Ktbase + n0;
#pragma unroll
    for (int k = 0; k < 10; ++k)
      gload16(ktrow + vt_src[k], smem + VT_OFF + (tid + 512 * k) * 16);
#pragma unroll
    for (int j = 0; j < 4; ++j) Sb[tid + 512 * j] = 0.f;
    __syncthreads();

    f32x4 sacc[2][2];
#pragma unroll
    for (int mt = 0; mt < 2; ++mt)
#pragma unroll
      for (int nt = 0; nt < 2; ++nt) sacc[mt][nt] = 0.0f;

#pragma unroll
    for (int ks = 0; ks < 8; ++ks) {
      bf16x8 kf[2];
#pragma unroll
      for (int nt = 0; nt < 2; ++nt) {
        int n = nt * 16 + l15;
        int d = wd * 256 + ks * 32 + lg * 8;
        int off = n * 2048 + ((d * 2) ^ ((n & 15) << 4));
        kf[nt] = *(const bf16x8*)(smem + KRM_OFF + off);
      }
#pragma unroll
      for (int mt = 0; mt < 2; ++mt)
#pragma unroll
        for (int nt = 0; nt < 2; ++nt)
          sacc[mt][nt] = __builtin_amdgcn_mfma_f32_16x16x32_bf16(
              qf[mt][ks], kf[nt], sacc[mt][nt], 0, 0, 0);
    }
#pragma unroll
    for (int mt = 0; mt < 2; ++mt)
#pragma unroll
      for (int nt = 0; nt < 2; ++nt)
#pragma unroll
        for (int i = 0; i < 4; ++i) {
          int r  = wm * 32 + mt * 16 + lg * 4 + i;
          int cc = nt * 16 + l15;
          atomicAdd(Sb + r * 32 + cc, sacc[mt][nt][i]);
        }
    __syncthreads();

    {
      const int row = tid >> 3;
      const int c0  = (tid & 7) * 4;
      float s0 = Sb[row * 32 + c0 + 0];
      float s1 = Sb[row * 32 + c0 + 1];
      float s2 = Sb[row * 32 + c0 + 2];
      float s3 = Sb[row * 32 + c0 + 3];
      float mx = fmaxf(fmaxf(s0, s1), fmaxf(s2, s3));
#pragma unroll
      for (int m = 1; m < 8; m <<= 1) mx = fmaxf(mx, __shfl_xor(mx, m, 8));
      const float Mold = RM[row];
      const float Mnew = fmaxf(Mold, mx);
      const float p0 = __expf(s0 - Mnew);
      const float p1 = __expf(s1 - Mnew);
      const float p2 = __expf(s2 - Mnew);
      const float p3 = __expf(s3 - Mnew);
      float ps = p0 + p1 + p2 + p3;
#pragma unroll
      for (int m = 1; m < 8; m <<= 1) ps += __shfl_xor(ps, m, 8);
      const float cfac = __expf(Mold - Mnew);
      if ((tid & 7) == 0) {
        RM[row] = Mnew;
        RS[row] = RS[row] * cfac + ps;
        CR[row] = cfac;
      }
      ushort4 pw;
      pw.x = f2bf(p0); pw.y = f2bf(p1); pw.z = f2bf(p2); pw.w = f2bf(p3);
      *(ushort4*)(smem + PBUF_OFF + row * 80 + c0 * 2) = pw;
    }
    __syncthreads();

    float cr[2][4];
#pragma unroll
    for (int mt = 0; mt < 2; ++mt)
#pragma unroll
      for (int i = 0; i < 4; ++i)
        cr[mt][i] = CR[wm * 32 + mt * 16 + lg * 4 + i];
#pragma unroll
    for (int mt = 0; mt < 2; ++mt)
#pragma unroll
      for (int dt = 0; dt < 16; ++dt)
#pragma unroll
        for (int i = 0; i < 4; ++i) acc[mt][dt][i] *= cr[mt][i];

    bf16x8 pf[2];
#pragma unroll
    for (int mt = 0; mt < 2; ++mt) {
      int r = wm * 32 + mt * 16 + l15;
      pf[mt] = *(const bf16x8*)(smem + PBUF_OFF + r * 80 + lg * 16);
    }
#pragma unroll
    for (int dt = 0; dt < 16; ++dt) {
      int d = wd * 256 + dt * 16 + l15;
      bf16x8 vf = *(const bf16x8*)(smem + VT_OFF + d * 80 + lg * 16);
#pragma unroll
      for (int mt = 0; mt < 2; ++mt)
        acc[mt][dt] = __builtin_amdgcn_mfma_f32_16x16x32_bf16(
            pf[mt], vf, acc[mt][dt], 0, 0, 0);
    }
  }

  float inv[2][4];
#pragma unroll
  for (int mt = 0; mt < 2; ++mt)
#pragma unroll
    for (int i = 0; i < 4; ++i)
      inv[mt][i] = 1.0f / RS[wm * 32 + mt * 16 + lg * 4 + i];
#pragma unroll
  for (int mt = 0; mt < 2; ++mt)
#pragma unroll
    for (int dt = 0; dt < 16; ++dt) {
      int d = wd * 256 + dt * 16 + l15;
#pragma unroll
      for (int i = 0; i < 4; ++i) {
        int r = q0 + wm * 32 + mt * 16 + lg * 4 + i;
        Out[((size_t)b * NSEQ + r) * DIMD + d] = acc[mt][dt][i] * inv[mt][i];
      }
    }
}

extern "C" void kernel_launch(void* const* d_in, const int* in_sizes, int n_in,
                              void* d_out, int out_size, void* d_ws, size_t ws_size,
                              hipStream_t stream) {
  const float* vis = (const float*)d_in[0];
  const float* txt = (const float*)d_in[1];
  const float* gv  = (const float*)d_in[2];
  const float* bv  = (const float*)d_in[3];
  const float* gt  = (const float*)d_in[4];
  const float* bt  = (const float*)d_in[5];
  float* out = (float*)d_out;

  const size_t tokens = (size_t)BATCH * NSEQ * DIMD;      // 33,554,432 elems
  ushort* Qbf = (ushort*)d_ws;                            // 64 MiB
  ushort* Kbf = Qbf + tokens;                             // 64 MiB
  ushort* Ktb = Kbf + tokens;                             // 64 MiB
  char*   wsb = (char*)d_ws;
  float*  Rsum = (float*)(wsb + 201326592);               // 128 KiB @ 192 MiB
  ushort* Sbuf = (ushort*)(wsb + 201457664);              // S region

  const size_t S_FULL  = (size_t)BATCH * NSEQ * NSEQ * 2; // 256 MiB
  const size_t S_ONE   = (size_t)NSEQ * NSEQ * 2;         // 32 MiB
  const size_t NEED_FULL = 201457664 + S_FULL;
  const size_t NEED_ONE  = 201457664 + S_ONE;

  // prep: LN (scale 1/sqrt(1024) folded into visual), V^T copy
  ln_bf16_kernel<<<BATCH * NSEQ / 4, 256, 0, stream>>>(vis, gv, bv, Qbf, 0.03125f);
  ln_bf16_kernel<<<BATCH * NSEQ / 4, 256, 0, stream>>>(txt, gt, bt, Kbf, 1.0f);
  transpose_kernel<<<BATCH * (NSEQ / 64) * (DIMD / 64), 256, 0, stream>>>(Kbf, Ktb);

  if (ws_size >= NEED_ONE) {
    hipMemsetAsync(Rsum, 0, (size_t)BATCH * NSEQ * sizeof(float), stream);
    if (ws_size >= NEED_FULL) {
      gemm1_kernel<<<dim3(32, 32, BATCH), 256, 0, stream>>>(
          Qbf, Kbf, Sbuf, Rsum, 0, (size_t)NSEQ * NSEQ);
      gemm2_kernel<<<dim3(8, 32, BATCH), 256, 0, stream>>>(
          Sbuf, Ktb, Rsum, out, 0, (size_t)NSEQ * NSEQ);
    } else {
      for (int b = 0; b < BATCH; ++b) {
        gemm1_kernel<<<dim3(32, 32, 1), 256, 0, stream>>>(
            Qbf, Kbf, Sbuf, Rsum, b, 0);
        gemm2_kernel<<<dim3(8, 32, 1), 256, 0, stream>>>(
            Sbuf, Ktb, Rsum, out, b, 0);
      }
    }
  } else {
    hipFuncSetAttribute((const void*)attn_kernel,
                        hipFuncAttributeMaxDynamicSharedMemorySize, LDS_TOTAL);
    attn_kernel<<<BATCH * (NSEQ / BM), 512, LDS_TOTAL, stream>>>(Qbf, Kbf, Ktb, out);
  }
}

// Round 3
// 801.663 us; speedup vs baseline: 5.0441x; 1.2404x over previous
//
#include <hip/hip_runtime.h>
#include <hip/hip_bf16.h>
#include <stdint.h>

#define DIMD 1024
#define NSEQ 4096
#define BATCH 8
#define LN_EPS 1e-5f

typedef __attribute__((ext_vector_type(8))) short bf16x8;
typedef __attribute__((ext_vector_type(4))) float f32x4;

__device__ __forceinline__ ushort f2bf(float f) {
  union { __hip_bfloat16 h; ushort u; } cv;
  cv.h = __float2bfloat16(f);
  return cv.u;
}

__device__ __forceinline__ void gload16(const void* g, void* l) {
  __builtin_amdgcn_global_load_lds(
      (const __attribute__((address_space(1))) uint32_t*)g,
      (__attribute__((address_space(3))) uint32_t*)l, 16, 0, 0);
}

// barriers for the 8-phase schedule.
// ENDBAR*: lgkmcnt(0) guarantees all this wave's ds_reads complete before the
// barrier (closes read-vs-prefetch-overwrite race); vmcnt(4) = counted wait
// keeping the 2 youngest chunks (4 loads) in flight.
#define MIDBAR()   asm volatile("s_barrier" ::: "memory")
#define ENDBAR()   asm volatile("s_waitcnt lgkmcnt(0)\n\ts_barrier" ::: "memory")
#define ENDBARV4() asm volatile("s_waitcnt vmcnt(4) lgkmcnt(0)\n\ts_barrier" ::: "memory")
#define ENDBARV0() asm volatile("s_waitcnt vmcnt(0) lgkmcnt(0)\n\ts_barrier" ::: "memory")

// ---------------- LayerNorm (fp32 in -> bf16 out, scale folded) -------------
__global__ __launch_bounds__(256) void ln_bf16_kernel(
    const float* __restrict__ x, const float* __restrict__ gamma,
    const float* __restrict__ beta, ushort* __restrict__ y, float scale)
{
  const int lane = threadIdx.x & 63;
  const int wv   = threadIdx.x >> 6;
  const size_t row = (size_t)blockIdx.x * 4 + wv;
  const float* xr = x + row * DIMD;

  float4 v[4];
#pragma unroll
  for (int c = 0; c < 4; ++c)
    v[c] = *(const float4*)(xr + c * 256 + lane * 4);

  float s = 0.f;
#pragma unroll
  for (int c = 0; c < 4; ++c) s += v[c].x + v[c].y + v[c].z + v[c].w;
#pragma unroll
  for (int m = 32; m >= 1; m >>= 1) s += __shfl_xor(s, m, 64);
  const float mean = s * (1.0f / DIMD);

  float vs = 0.f;
#pragma unroll
  for (int c = 0; c < 4; ++c) {
    float a0 = v[c].x - mean, a1 = v[c].y - mean;
    float a2 = v[c].z - mean, a3 = v[c].w - mean;
    vs += a0 * a0 + a1 * a1 + a2 * a2 + a3 * a3;
  }
#pragma unroll
  for (int m = 32; m >= 1; m >>= 1) vs += __shfl_xor(vs, m, 64);
  const float rstd = rsqrtf(vs * (1.0f / DIMD) + LN_EPS);

  ushort* yr = y + row * DIMD;
#pragma unroll
  for (int c = 0; c < 4; ++c) {
    const int d = c * 256 + lane * 4;
    float4 g  = *(const float4*)(gamma + d);
    float4 bb = *(const float4*)(beta + d);
    ushort4 o;
    o.x = f2bf(((v[c].x - mean) * rstd * g.x + bb.x) * scale);
    o.y = f2bf(((v[c].y - mean) * rstd * g.y + bb.y) * scale);
    o.z = f2bf(((v[c].z - mean) * rstd * g.z + bb.z) * scale);
    o.w = f2bf(((v[c].w - mean) * rstd * g.w + bb.w) * scale);
    *(ushort4*)(yr + d) = o;
  }
}

// ---------------- bf16 transpose: [b][n][d] -> [b][d][n] --------------------
__global__ __launch_bounds__(256) void transpose_kernel(
    const ushort* __restrict__ src, ushort* __restrict__ dst)
{
  __shared__ ushort tile[64][72];
  const int t   = threadIdx.x;
  const int bid = blockIdx.x;
  const int b   = bid >> 10;
  const int rem = bid & 1023;
  const int n0  = (rem >> 4) << 6;
  const int d0  = (rem & 15) << 6;
  const ushort* sb = src + ((size_t)b * NSEQ) * DIMD;
  ushort* db       = dst + ((size_t)b * DIMD) * NSEQ;

#pragma unroll
  for (int k = 0; k < 2; ++k) {
    int c = t + 256 * k;
    int r = c >> 3, scol = (c & 7) * 8;
    *(uint4*)&tile[r][scol] =
        *(const uint4*)(sb + (size_t)(n0 + r) * DIMD + d0 + scol);
  }
  __syncthreads();
#pragma unroll
  for (int k = 0; k < 2; ++k) {
    int c = t + 256 * k;
    int dr = c >> 3, ns = (c & 7) * 8;
    union { ushort u[8]; uint4 q; } tv;
#pragma unroll
    for (int i = 0; i < 8; ++i) tv.u[i] = tile[ns + i][dr];
    *(uint4*)(db + (size_t)(d0 + dr) * NSEQ + n0 + ns) = tv.q;
  }
}

// ================== 256x256 8-phase GEMM core ===============================
// 512 thr = 8 waves (2M x 4N). Wave tile 128x64. BK=64 as 2 k-half chunks of
// [256 rows][32 cols] bf16 (16 KB each) -> frag reads are bank-conflict-free
// with NO swizzle (lane(r,lg) hits bank (r*16+lg*4)%32; exactly 8/bank).
// LDS: 2 dbuf x {A-k0, A-k1, B-k0, B-k1} = 8 x 16 KB = 128 KB.
// Per K-tile: 4 phases {ds-read frags | stage 1 next chunk | bar | 16 MFMA |
// endbar}, counted vmcnt(4) at phases 2 & 4 only.

__device__ __forceinline__ void stage_chunk(const ushort* __restrict__ g,
                                            int ld, char* l, int tid) {
  const int r = tid >> 2;            // 0..127
  const int c = (tid & 3) * 8;       // 0,8,16,24
  gload16(g + (size_t)r * ld + c,          l + tid * 16);
  gload16(g + (size_t)(r + 128) * ld + c,  l + tid * 16 + 8192);
}

__device__ __forceinline__ void read_af(const ushort* Ac, int wm, int mh,
                                        int l15, int lg, bf16x8 (&af)[4]) {
#pragma unroll
  for (int m = 0; m < 4; ++m)
    af[m] = *(const bf16x8*)(Ac + (wm * 128 + (mh * 4 + m) * 16 + l15) * 32 + lg * 8);
}
__device__ __forceinline__ void read_bf(const ushort* Bc, int wn,
                                        int l15, int lg, bf16x8 (&bf)[4]) {
#pragma unroll
  for (int n = 0; n < 4; ++n)
    bf[n] = *(const bf16x8*)(Bc + (wn * 64 + n * 16 + l15) * 32 + lg * 8);
}

__device__ __forceinline__ void gemm_core_256(
    const ushort* __restrict__ Ab, const ushort* __restrict__ Bb,
    int lda, int ldb, int NT, char* smem, f32x4 (&acc)[8][4],
    int tid, int wm, int wn, int l15, int lg)
{
  // prologue: tile 0 -> buf0, issue order [Ak0, Bk0, Ak1, Bk1]
  stage_chunk(Ab,      lda, smem + 0,     tid);
  stage_chunk(Bb,      ldb, smem + 32768, tid);
  stage_chunk(Ab + 32, lda, smem + 16384, tid);
  stage_chunk(Bb + 32, ldb, smem + 49152, tid);
  ENDBARV4();  // completes Ak0,Bk0; keeps Ak1,Bk1 in flight

  for (int kt = 0; kt < NT; ++kt) {
    char* cb = smem + (kt & 1) * 65536;
    char* nbuf = smem + (((kt & 1) ^ 1) * 65536);
    const ushort* An = Ab + (size_t)(kt + 1) * 64;
    const ushort* Bn = Bb + (size_t)(kt + 1) * 64;
    const bool pf = (kt + 1 < NT);
    const ushort* A0 = (const ushort*)(cb);
    const ushort* A1 = (const ushort*)(cb + 16384);
    const ushort* B0 = (const ushort*)(cb + 32768);
    const ushort* B1 = (const ushort*)(cb + 49152);
    bf16x8 af[4], bf[4];

    // ---- phase 0: kh0, m-frags 0-3 (+B frags kh0), prefetch next.Ak0 ----
    read_af(A0, wm, 0, l15, lg, af);
    read_bf(B0, wn, l15, lg, bf);
    if (pf) stage_chunk(An, lda, nbuf + 0, tid);
    MIDBAR();
    __builtin_amdgcn_s_setprio(1);
#pragma unroll
    for (int m = 0; m < 4; ++m)
#pragma unroll
      for (int n = 0; n < 4; ++n)
        acc[m][n] = __builtin_amdgcn_mfma_f32_16x16x32_bf16(af[m], bf[n], acc[m][n], 0, 0, 0);
    __builtin_amdgcn_s_setprio(0);
    ENDBAR();

    // ---- phase 1: kh0, m-frags 4-7 (B cached), prefetch next.Bk0 ----
    read_af(A0, wm, 1, l15, lg, af);
    if (pf) stage_chunk(Bn, ldb, nbuf + 32768, tid);
    MIDBAR();
    __builtin_amdgcn_s_setprio(1);
#pragma unroll
    for (int m = 0; m < 4; ++m)
#pragma unroll
      for (int n = 0; n < 4; ++n)
        acc[4 + m][n] = __builtin_amdgcn_mfma_f32_16x16x32_bf16(af[m], bf[n], acc[4 + m][n], 0, 0, 0);
    __builtin_amdgcn_s_setprio(0);
    if (pf) { ENDBARV4(); } else { ENDBARV0(); }  // confirm cur k1 chunks

    // ---- phase 2: kh1, m-frags 0-3 (+B frags kh1), prefetch next.Ak1 ----
    read_af(A1, wm, 0, l15, lg, af);
    read_bf(B1, wn, l15, lg, bf);
    if (pf) stage_chunk(An + 32, lda, nbuf + 16384, tid);
    MIDBAR();
    __builtin_amdgcn_s_setprio(1);
#pragma unroll
    for (int m = 0; m < 4; ++m)
#pragma unroll
      for (int n = 0; n < 4; ++n)
        acc[m][n] = __builtin_amdgcn_mfma_f32_16x16x32_bf16(af[m], bf[n], acc[m][n], 0, 0, 0);
    __builtin_amdgcn_s_setprio(0);
    ENDBAR();

    // ---- phase 3: kh1, m-frags 4-7, prefetch next.Bk1 ----
    read_af(A1, wm, 1, l15, lg, af);
    if (pf) stage_chunk(Bn + 32, ldb, nbuf + 49152, tid);
    MIDBAR();
    __builtin_amdgcn_s_setprio(1);
#pragma unroll
    for (int m = 0; m < 4; ++m)
#pragma unroll
      for (int n = 0; n < 4; ++n)
        acc[4 + m][n] = __builtin_amdgcn_mfma_f32_16x16x32_bf16(af[m], bf[n], acc[4 + m][n], 0, 0, 0);
    __builtin_amdgcn_s_setprio(0);
    if (pf) { ENDBARV4(); } else { ENDBAR(); }  // confirm next k0 chunks
  }
}

// GEMM1: S = exp(Q.K^T), row-sums via atomics. M=N=4096, K=1024.
__global__ __launch_bounds__(512, 2) void gemm1_256(
    const ushort* __restrict__ Q, const ushort* __restrict__ K,
    ushort* __restrict__ S, float* __restrict__ Rsum,
    int b0, size_t s_stride)
{
  extern __shared__ char smem[];
  const int tid  = threadIdx.x;
  const int lane = tid & 63;
  const int wave = tid >> 6;
  const int wm = wave >> 2, wn = wave & 3;
  const int l15 = lane & 15, lg = lane >> 4;

  const int lid   = blockIdx.x + (blockIdx.y << 4) + (blockIdx.z << 8);
  const int total = (int)(gridDim.x * gridDim.y * gridDim.z);
  const int swz   = (lid & 7) * (total >> 3) + (lid >> 3);
  const int bx = swz & 15, by = (swz >> 4) & 15, bzc = swz >> 8;

  const int bz   = b0 + bzc;
  const int row0 = by * 256, col0 = bx * 256;
  const ushort* Ab = Q + (size_t)bz * NSEQ * DIMD + (size_t)row0 * DIMD;
  const ushort* Bb = K + (size_t)bz * NSEQ * DIMD + (size_t)col0 * DIMD;

  f32x4 acc[8][4];
#pragma unroll
  for (int m = 0; m < 8; ++m)
#pragma unroll
    for (int n = 0; n < 4; ++n) acc[m][n] = 0.0f;

  gemm_core_256(Ab, Bb, DIMD, DIMD, DIMD / 64, smem, acc, tid, wm, wn, l15, lg);

  // epilogue: p=exp(s) (|s|<=32, f32-safe), bf16 store, rowsum atomics.
  ushort* Sb = S + (size_t)bzc * s_stride;
  float*  Rs = Rsum + (size_t)bz * NSEQ;
#pragma unroll
  for (int mi = 0; mi < 8; ++mi) {
    float rsum[4] = {0.f, 0.f, 0.f, 0.f};
#pragma unroll
    for (int ni = 0; ni < 4; ++ni) {
      const int c = col0 + wn * 64 + ni * 16 + l15;
#pragma unroll
      for (int i = 0; i < 4; ++i) {
        const int r = row0 + wm * 128 + mi * 16 + lg * 4 + i;
        float p = __expf(acc[mi][ni][i]);
        Sb[(size_t)r * NSEQ + c] = f2bf(p);
        rsum[i] += p;
      }
    }
#pragma unroll
    for (int i = 0; i < 4; ++i) {
      float v = rsum[i];
      v += __shfl_xor(v, 1, 64);
      v += __shfl_xor(v, 2, 64);
      v += __shfl_xor(v, 4, 64);
      v += __shfl_xor(v, 8, 64);
      if (l15 == 0)
        atomicAdd(Rs + row0 + wm * 128 + mi * 16 + lg * 4 + i, v);
    }
  }
}

// GEMM2: O = (S.V)/Rsum. M=4096, N=1024, K=4096. B = V^T (=Kt).
__global__ __launch_bounds__(512, 2) void gemm2_256(
    const ushort* __restrict__ S, const ushort* __restrict__ Kt,
    const float* __restrict__ Rsum, float* __restrict__ Out,
    int b0, size_t s_stride)
{
  extern __shared__ char smem[];
  const int tid  = threadIdx.x;
  const int lane = tid & 63;
  const int wave = tid >> 6;
  const int wm = wave >> 2, wn = wave & 3;
  const int l15 = lane & 15, lg = lane >> 4;

  const int lid   = blockIdx.x + (blockIdx.y << 2) + (blockIdx.z << 6);
  const int total = (int)(gridDim.x * gridDim.y * gridDim.z);
  const int swz   = (lid & 7) * (total >> 3) + (lid >> 3);
  const int bx = swz & 3, by = (swz >> 2) & 15, bzc = swz >> 6;

  const int bz   = b0 + bzc;
  const int row0 = by * 256;   // v rows
  const int col0 = bx * 256;   // d cols
  const ushort* Ab = S  + (size_t)bzc * s_stride + (size_t)row0 * NSEQ;
  const ushort* Bb = Kt + ((size_t)bz * DIMD + col0) * NSEQ;

  f32x4 acc[8][4];
#pragma unroll
  for (int m = 0; m < 8; ++m)
#pragma unroll
    for (int n = 0; n < 4; ++n) acc[m][n] = 0.0f;

  gemm_core_256(Ab, Bb, NSEQ, NSEQ, NSEQ / 64, smem, acc, tid, wm, wn, l15, lg);

  const float* Rs = Rsum + (size_t)bz * NSEQ;
  float* Ob = Out + (size_t)bz * NSEQ * DIMD;
#pragma unroll
  for (int mi = 0; mi < 8; ++mi) {
#pragma unroll
    for (int i = 0; i < 4; ++i) {
      const int r = row0 + wm * 128 + mi * 16 + lg * 4 + i;
      const float inv = 1.0f / Rs[r];
#pragma unroll
      for (int ni = 0; ni < 4; ++ni) {
        const int c = col0 + wn * 64 + ni * 16 + l15;
        Ob[(size_t)r * DIMD + c] = acc[mi][ni][i] * inv;
      }
    }
  }
}

extern "C" void kernel_launch(void* const* d_in, const int* in_sizes, int n_in,
                              void* d_out, int out_size, void* d_ws, size_t ws_size,
                              hipStream_t stream) {
  const float* vis = (const float*)d_in[0];
  const float* txt = (const float*)d_in[1];
  const float* gv  = (const float*)d_in[2];
  const float* bv  = (const float*)d_in[3];
  const float* gt  = (const float*)d_in[4];
  const float* bt  = (const float*)d_in[5];
  float* out = (float*)d_out;

  const size_t tokens = (size_t)BATCH * NSEQ * DIMD;      // 33,554,432 elems
  ushort* Qbf = (ushort*)d_ws;                            // 64 MiB
  ushort* Kbf = Qbf + tokens;                             // 64 MiB
  ushort* Ktb = Kbf + tokens;                             // 64 MiB
  char*   wsb = (char*)d_ws;
  float*  Rsum = (float*)(wsb + 201326592);               // @192 MiB
  ushort* Sbuf = (ushort*)(wsb + 201457664);              // S region

  const size_t S_FULL = (size_t)BATCH * NSEQ * NSEQ * 2;  // 256 MiB
  const size_t NEED_FULL = 201457664 + S_FULL;

  ln_bf16_kernel<<<BATCH * NSEQ / 4, 256, 0, stream>>>(vis, gv, bv, Qbf, 0.03125f);
  ln_bf16_kernel<<<BATCH * NSEQ / 4, 256, 0, stream>>>(txt, gt, bt, Kbf, 1.0f);
  transpose_kernel<<<BATCH * (NSEQ / 64) * (DIMD / 64), 256, 0, stream>>>(Kbf, Ktb);

  hipFuncSetAttribute((const void*)gemm1_256,
                      hipFuncAttributeMaxDynamicSharedMemorySize, 131072);
  hipFuncSetAttribute((const void*)gemm2_256,
                      hipFuncAttributeMaxDynamicSharedMemorySize, 131072);

  hipMemsetAsync(Rsum, 0, (size_t)BATCH * NSEQ * sizeof(float), stream);

  if (ws_size >= NEED_FULL) {
    gemm1_256<<<dim3(16, 16, BATCH), 512, 131072, stream>>>(
        Qbf, Kbf, Sbuf, Rsum, 0, (size_t)NSEQ * NSEQ);
    gemm2_256<<<dim3(4, 16, BATCH), 512, 131072, stream>>>(
        Sbuf, Ktb, Rsum, out, 0, (size_t)NSEQ * NSEQ);
  } else {
    for (int b = 0; b < BATCH; ++b) {
      gemm1_256<<<dim3(16, 16, 1), 512, 131072, stream>>>(
          Qbf, Kbf, Sbuf, Rsum, b, 0);
      gemm2_256<<<dim3(4, 16, 1), 512, 131072, stream>>>(
          Sbuf, Ktb, Rsum, out, b, 0);
    }
  }
}

// Round 4
// 774.610 us; speedup vs baseline: 5.2203x; 1.0349x over previous
//
#include <hip/hip_runtime.h>
#include <hip/hip_bf16.h>
#include <stdint.h>

#define DIMD 1024
#define NSEQ 4096
#define BATCH 8
#define LN_EPS 1e-5f

typedef __attribute__((ext_vector_type(8))) short bf16x8;
typedef __attribute__((ext_vector_type(4))) float f32x4;

__device__ __forceinline__ ushort f2bf(float f) {
  union { __hip_bfloat16 h; ushort u; } cv;
  cv.h = __float2bfloat16(f);
  return cv.u;
}

__device__ __forceinline__ void gload16(const void* g, void* l) {
  __builtin_amdgcn_global_load_lds(
      (const __attribute__((address_space(1))) uint32_t*)g,
      (__attribute__((address_space(3))) uint32_t*)l, 16, 0, 0);
}

// barriers for the 8-phase schedule (verified in round 3 — do not touch).
#define MIDBAR()   asm volatile("s_barrier" ::: "memory")
#define ENDBAR()   asm volatile("s_waitcnt lgkmcnt(0)\n\ts_barrier" ::: "memory")
#define ENDBARV4() asm volatile("s_waitcnt vmcnt(4) lgkmcnt(0)\n\ts_barrier" ::: "memory")
#define ENDBARV0() asm volatile("s_waitcnt vmcnt(0) lgkmcnt(0)\n\ts_barrier" ::: "memory")

// ---------------- LayerNorm (fp32 in -> bf16 out, scale folded) -------------
__global__ __launch_bounds__(256) void ln_bf16_kernel(
    const float* __restrict__ x, const float* __restrict__ gamma,
    const float* __restrict__ beta, ushort* __restrict__ y, float scale)
{
  const int lane = threadIdx.x & 63;
  const int wv   = threadIdx.x >> 6;
  const size_t row = (size_t)blockIdx.x * 4 + wv;
  const float* xr = x + row * DIMD;

  float4 v[4];
#pragma unroll
  for (int c = 0; c < 4; ++c)
    v[c] = *(const float4*)(xr + c * 256 + lane * 4);

  float s = 0.f;
#pragma unroll
  for (int c = 0; c < 4; ++c) s += v[c].x + v[c].y + v[c].z + v[c].w;
#pragma unroll
  for (int m = 32; m >= 1; m >>= 1) s += __shfl_xor(s, m, 64);
  const float mean = s * (1.0f / DIMD);

  float vs = 0.f;
#pragma unroll
  for (int c = 0; c < 4; ++c) {
    float a0 = v[c].x - mean, a1 = v[c].y - mean;
    float a2 = v[c].z - mean, a3 = v[c].w - mean;
    vs += a0 * a0 + a1 * a1 + a2 * a2 + a3 * a3;
  }
#pragma unroll
  for (int m = 32; m >= 1; m >>= 1) vs += __shfl_xor(vs, m, 64);
  const float rstd = rsqrtf(vs * (1.0f / DIMD) + LN_EPS);

  ushort* yr = y + row * DIMD;
#pragma unroll
  for (int c = 0; c < 4; ++c) {
    const int d = c * 256 + lane * 4;
    float4 g  = *(const float4*)(gamma + d);
    float4 bb = *(const float4*)(beta + d);
    ushort4 o;
    o.x = f2bf(((v[c].x - mean) * rstd * g.x + bb.x) * scale);
    o.y = f2bf(((v[c].y - mean) * rstd * g.y + bb.y) * scale);
    o.z = f2bf(((v[c].z - mean) * rstd * g.z + bb.z) * scale);
    o.w = f2bf(((v[c].w - mean) * rstd * g.w + bb.w) * scale);
    *(ushort4*)(yr + d) = o;
  }
}

// ---------------- bf16 transpose: [b][n][d] -> [b][d][n] --------------------
__global__ __launch_bounds__(256) void transpose_kernel(
    const ushort* __restrict__ src, ushort* __restrict__ dst)
{
  __shared__ ushort tile[64][72];
  const int t   = threadIdx.x;
  const int bid = blockIdx.x;
  const int b   = bid >> 10;
  const int rem = bid & 1023;
  const int n0  = (rem >> 4) << 6;
  const int d0  = (rem & 15) << 6;
  const ushort* sb = src + ((size_t)b * NSEQ) * DIMD;
  ushort* db       = dst + ((size_t)b * DIMD) * NSEQ;

#pragma unroll
  for (int k = 0; k < 2; ++k) {
    int c = t + 256 * k;
    int r = c >> 3, scol = (c & 7) * 8;
    *(uint4*)&tile[r][scol] =
        *(const uint4*)(sb + (size_t)(n0 + r) * DIMD + d0 + scol);
  }
  __syncthreads();
#pragma unroll
  for (int k = 0; k < 2; ++k) {
    int c = t + 256 * k;
    int dr = c >> 3, ns = (c & 7) * 8;
    union { ushort u[8]; uint4 q; } tv;
#pragma unroll
    for (int i = 0; i < 8; ++i) tv.u[i] = tile[ns + i][dr];
    *(uint4*)(db + (size_t)(d0 + dr) * NSEQ + n0 + ns) = tv.q;
  }
}

// ================== 256x256 8-phase GEMM core ===============================
// 512 thr = 8 waves. "A" operand = the 8-frag (C-row) operand, "B" = the
// 4-frag cached (C-col) operand. Wave roles: wm = wave>>2 selects the 128-wide
// C-row half, wn = wave&3 the 64-wide C-col quarter. BK=64 as 2 k-half chunks
// of [256 rows][32 cols] bf16 (16 KB). LDS: 2 dbuf x 4 chunks = 128 KB.
// Counted vmcnt(4) at phases 1 & 3 only (2 chunks = 4 loads stay in flight).

__device__ __forceinline__ void stage_chunk(const ushort* __restrict__ g,
                                            int ld, char* l, int tid) {
  const int r = tid >> 2;            // 0..127
  const int c = (tid & 3) * 8;       // 0,8,16,24
  gload16(g + (size_t)r * ld + c,          l + tid * 16);
  gload16(g + (size_t)(r + 128) * ld + c,  l + tid * 16 + 8192);
}

__device__ __forceinline__ void read_af(const ushort* Ac, int wm, int mh,
                                        int l15, int lg, bf16x8 (&af)[4]) {
#pragma unroll
  for (int m = 0; m < 4; ++m)
    af[m] = *(const bf16x8*)(Ac + (wm * 128 + (mh * 4 + m) * 16 + l15) * 32 + lg * 8);
}
__device__ __forceinline__ void read_bf(const ushort* Bc, int wn,
                                        int l15, int lg, bf16x8 (&bf)[4]) {
#pragma unroll
  for (int n = 0; n < 4; ++n)
    bf[n] = *(const bf16x8*)(Bc + (wn * 64 + n * 16 + l15) * 32 + lg * 8);
}

__device__ __forceinline__ void gemm_core_256(
    const ushort* __restrict__ Ab, const ushort* __restrict__ Bb,
    int lda, int ldb, int NT, char* smem, f32x4 (&acc)[8][4],
    int tid, int wm, int wn, int l15, int lg)
{
  // prologue: tile 0 -> buf0, issue order [Ak0, Bk0, Ak1, Bk1]
  stage_chunk(Ab,      lda, smem + 0,     tid);
  stage_chunk(Bb,      ldb, smem + 32768, tid);
  stage_chunk(Ab + 32, lda, smem + 16384, tid);
  stage_chunk(Bb + 32, ldb, smem + 49152, tid);
  ENDBARV4();  // completes Ak0,Bk0; keeps Ak1,Bk1 in flight

  for (int kt = 0; kt < NT; ++kt) {
    char* cb = smem + (kt & 1) * 65536;
    char* nbuf = smem + (((kt & 1) ^ 1) * 65536);
    const ushort* An = Ab + (size_t)(kt + 1) * 64;
    const ushort* Bn = Bb + (size_t)(kt + 1) * 64;
    const bool pf = (kt + 1 < NT);
    const ushort* A0 = (const ushort*)(cb);
    const ushort* A1 = (const ushort*)(cb + 16384);
    const ushort* B0 = (const ushort*)(cb + 32768);
    const ushort* B1 = (const ushort*)(cb + 49152);
    bf16x8 af[4], bf[4];

    // ---- phase 0: kh0, a-frags 0-3 + b-frags, prefetch next.Ak0 ----
    read_af(A0, wm, 0, l15, lg, af);
    read_bf(B0, wn, l15, lg, bf);
    if (pf) stage_chunk(An, lda, nbuf + 0, tid);
    MIDBAR();
    __builtin_amdgcn_s_setprio(1);
#pragma unroll
    for (int m = 0; m < 4; ++m)
#pragma unroll
      for (int n = 0; n < 4; ++n)
        acc[m][n] = __builtin_amdgcn_mfma_f32_16x16x32_bf16(af[m], bf[n], acc[m][n], 0, 0, 0);
    __builtin_amdgcn_s_setprio(0);
    ENDBAR();

    // ---- phase 1: kh0, a-frags 4-7 (B cached), prefetch next.Bk0 ----
    read_af(A0, wm, 1, l15, lg, af);
    if (pf) stage_chunk(Bn, ldb, nbuf + 32768, tid);
    MIDBAR();
    __builtin_amdgcn_s_setprio(1);
#pragma unroll
    for (int m = 0; m < 4; ++m)
#pragma unroll
      for (int n = 0; n < 4; ++n)
        acc[4 + m][n] = __builtin_amdgcn_mfma_f32_16x16x32_bf16(af[m], bf[n], acc[4 + m][n], 0, 0, 0);
    __builtin_amdgcn_s_setprio(0);
    if (pf) { ENDBARV4(); } else { ENDBARV0(); }

    // ---- phase 2: kh1, a-frags 0-3 + b-frags, prefetch next.Ak1 ----
    read_af(A1, wm, 0, l15, lg, af);
    read_bf(B1, wn, l15, lg, bf);
    if (pf) stage_chunk(An + 32, lda, nbuf + 16384, tid);
    MIDBAR();
    __builtin_amdgcn_s_setprio(1);
#pragma unroll
    for (int m = 0; m < 4; ++m)
#pragma unroll
      for (int n = 0; n < 4; ++n)
        acc[m][n] = __builtin_amdgcn_mfma_f32_16x16x32_bf16(af[m], bf[n], acc[m][n], 0, 0, 0);
    __builtin_amdgcn_s_setprio(0);
    ENDBAR();

    // ---- phase 3: kh1, a-frags 4-7, prefetch next.Bk1 ----
    read_af(A1, wm, 1, l15, lg, af);
    if (pf) stage_chunk(Bn + 32, ldb, nbuf + 49152, tid);
    MIDBAR();
    __builtin_amdgcn_s_setprio(1);
#pragma unroll
    for (int m = 0; m < 4; ++m)
#pragma unroll
      for (int n = 0; n < 4; ++n)
        acc[4 + m][n] = __builtin_amdgcn_mfma_f32_16x16x32_bf16(af[m], bf[n], acc[4 + m][n], 0, 0, 0);
    __builtin_amdgcn_s_setprio(0);
    if (pf) { ENDBARV4(); } else { ENDBAR(); }
  }
}

// GEMM1: S = exp(Q.K^T) stored [v][t] row-major; row-sums via atomics.
// OPERAND-SWAPPED: af = K-frags (C rows = t), bf = Q-frags (C cols = v) so
// each lane owns 4 contiguous t -> 8B vector stores along S's fast dim.
__global__ __launch_bounds__(512, 2) void gemm1_256(
    const ushort* __restrict__ Q, const ushort* __restrict__ K,
    ushort* __restrict__ S, float* __restrict__ Rsum,
    int b0, size_t s_stride)
{
  extern __shared__ char smem[];
  const int tid  = threadIdx.x;
  const int lane = tid & 63;
  const int wave = tid >> 6;
  const int wm = wave >> 2, wn = wave & 3;
  const int l15 = lane & 15, lg = lane >> 4;

  int bx, by, bzc;
  if (gridDim.z == BATCH) {
    // batch-per-XCD: hw linear id % 8 selects XCD (empirical round-robin);
    // pin batch to XCD, sweep bx fastest within (Q-panel L2 reuse).
    const int hw = blockIdx.x + (blockIdx.y << 4) + (blockIdx.z << 8);
    bzc = hw & 7;
    const int inner = hw >> 3;
    bx = inner & 15; by = (inner >> 4) & 15;
  } else {
    bx = blockIdx.x; by = blockIdx.y; bzc = 0;
  }

  const int bz   = b0 + bzc;
  const int row0 = by * 256, col0 = bx * 256;   // row0 = v (Q), col0 = t (K)
  const ushort* Qb = Q + (size_t)bz * NSEQ * DIMD + (size_t)row0 * DIMD;
  const ushort* Kb = K + (size_t)bz * NSEQ * DIMD + (size_t)col0 * DIMD;

  f32x4 acc[8][4];
#pragma unroll
  for (int m = 0; m < 8; ++m)
#pragma unroll
    for (int n = 0; n < 4; ++n) acc[m][n] = 0.0f;

  // swapped: A-role (8 frags, C-rows=t) = K tile; B-role (4 frags, C-cols=v) = Q tile
  gemm_core_256(Kb, Qb, DIMD, DIMD, DIMD / 64, smem, acc, tid, wm, wn, l15, lg);

  // epilogue: acc[ti][vi][i] = S-hat[t = col0+wm*128+ti*16+lg*4+i][v = row0+wn*64+vi*16+l15]
  ushort* Sb = S + (size_t)bzc * s_stride;
  float*  Rs = Rsum + (size_t)bz * NSEQ;
  float vsum[4] = {0.f, 0.f, 0.f, 0.f};
#pragma unroll
  for (int ti = 0; ti < 8; ++ti) {
#pragma unroll
    for (int vi = 0; vi < 4; ++vi) {
      const int v = row0 + wn * 64 + vi * 16 + l15;
      const int t = col0 + wm * 128 + ti * 16 + lg * 4;
      float p0 = __expf(acc[ti][vi][0]);
      float p1 = __expf(acc[ti][vi][1]);
      float p2 = __expf(acc[ti][vi][2]);
      float p3 = __expf(acc[ti][vi][3]);
      vsum[vi] += (p0 + p1) + (p2 + p3);
      unsigned long long pk =
          (unsigned long long)f2bf(p0)        |
          ((unsigned long long)f2bf(p1) << 16) |
          ((unsigned long long)f2bf(p2) << 32) |
          ((unsigned long long)f2bf(p3) << 48);
      __builtin_nontemporal_store(
          pk, (unsigned long long*)(Sb + (size_t)v * NSEQ + t));
    }
  }
#pragma unroll
  for (int vi = 0; vi < 4; ++vi) {
    float s = vsum[vi];
    s += __shfl_xor(s, 16, 64);
    s += __shfl_xor(s, 32, 64);
    if (lg == 0)
      atomicAdd(Rs + row0 + wn * 64 + vi * 16 + l15, s);
  }
}

// GEMM2: O = (S.V)/Rsum stored [v][d] row-major. OPERAND-SWAPPED:
// af = Vt-frags (C rows = d), bf = S-frags (C cols = v) -> 16B f32x4 stores.
__global__ __launch_bounds__(512, 2) void gemm2_256(
    const ushort* __restrict__ S, const ushort* __restrict__ Kt,
    const float* __restrict__ Rsum, float* __restrict__ Out,
    int b0, size_t s_stride)
{
  extern __shared__ char smem[];
  const int tid  = threadIdx.x;
  const int lane = tid & 63;
  const int wave = tid >> 6;
  const int wm = wave >> 2, wn = wave & 3;
  const int l15 = lane & 15, lg = lane >> 4;

  int bx, by, bzc;
  if (gridDim.z == BATCH) {
    const int hw = blockIdx.x + (blockIdx.y << 2) + (blockIdx.z << 6);
    bzc = hw & 7;
    const int inner = hw >> 3;
    bx = inner & 3; by = inner >> 2;
  } else {
    bx = blockIdx.x; by = blockIdx.y; bzc = 0;
  }

  const int bz   = b0 + bzc;
  const int row0 = by * 256;   // v rows
  const int col0 = bx * 256;   // d cols
  const ushort* Sb2 = S  + (size_t)bzc * s_stride + (size_t)row0 * NSEQ;
  const ushort* Vtb = Kt + ((size_t)bz * DIMD + col0) * NSEQ;

  f32x4 acc[8][4];
#pragma unroll
  for (int m = 0; m < 8; ++m)
#pragma unroll
    for (int n = 0; n < 4; ++n) acc[m][n] = 0.0f;

  // swapped: A-role (8 frags, C-rows=d) = Vt tile; B-role (C-cols=v) = S tile
  gemm_core_256(Vtb, Sb2, NSEQ, NSEQ, NSEQ / 64, smem, acc, tid, wm, wn, l15, lg);

  // epilogue: acc[di][vi][i] = O[v = row0+wn*64+vi*16+l15][d = col0+wm*128+di*16+lg*4+i]
  const float* Rs = Rsum + (size_t)bz * NSEQ;
  float* Ob = Out + (size_t)bz * NSEQ * DIMD;
  float inv[4];
#pragma unroll
  for (int vi = 0; vi < 4; ++vi)
    inv[vi] = 1.0f / Rs[row0 + wn * 64 + vi * 16 + l15];
#pragma unroll
  for (int di = 0; di < 8; ++di) {
#pragma unroll
    for (int vi = 0; vi < 4; ++vi) {
      const int v = row0 + wn * 64 + vi * 16 + l15;
      const int d = col0 + wm * 128 + di * 16 + lg * 4;
      f32x4 o = acc[di][vi] * inv[vi];
      __builtin_nontemporal_store(
          o, (f32x4*)(Ob + (size_t)v * DIMD + d));
    }
  }
}

extern "C" void kernel_launch(void* const* d_in, const int* in_sizes, int n_in,
                              void* d_out, int out_size, void* d_ws, size_t ws_size,
                              hipStream_t stream) {
  const float* vis = (const float*)d_in[0];
  const float* txt = (const float*)d_in[1];
  const float* gv  = (const float*)d_in[2];
  const float* bv  = (const float*)d_in[3];
  const float* gt  = (const float*)d_in[4];
  const float* bt  = (const float*)d_in[5];
  float* out = (float*)d_out;

  const size_t tokens = (size_t)BATCH * NSEQ * DIMD;      // 33,554,432 elems
  ushort* Qbf = (ushort*)d_ws;                            // 64 MiB
  ushort* Kbf = Qbf + tokens;                             // 64 MiB
  ushort* Ktb = Kbf + tokens;                             // 64 MiB
  char*   wsb = (char*)d_ws;
  float*  Rsum = (float*)(wsb + 201326592);               // @192 MiB
  ushort* Sbuf = (ushort*)(wsb + 201457664);              // S region

  const size_t S_FULL = (size_t)BATCH * NSEQ * NSEQ * 2;  // 256 MiB
  const size_t NEED_FULL = 201457664 + S_FULL;

  ln_bf16_kernel<<<BATCH * NSEQ / 4, 256, 0, stream>>>(vis, gv, bv, Qbf, 0.03125f);
  ln_bf16_kernel<<<BATCH * NSEQ / 4, 256, 0, stream>>>(txt, gt, bt, Kbf, 1.0f);
  transpose_kernel<<<BATCH * (NSEQ / 64) * (DIMD / 64), 256, 0, stream>>>(Kbf, Ktb);

  hipFuncSetAttribute((const void*)gemm1_256,
                      hipFuncAttributeMaxDynamicSharedMemorySize, 131072);
  hipFuncSetAttribute((const void*)gemm2_256,
                      hipFuncAttributeMaxDynamicSharedMemorySize, 131072);

  hipMemsetAsync(Rsum, 0, (size_t)BATCH * NSEQ * sizeof(float), stream);

  if (ws_size >= NEED_FULL) {
    gemm1_256<<<dim3(16, 16, BATCH), 512, 131072, stream>>>(
        Qbf, Kbf, Sbuf, Rsum, 0, (size_t)NSEQ * NSEQ);
    gemm2_256<<<dim3(4, 16, BATCH), 512, 131072, stream>>>(
        Sbuf, Ktb, Rsum, out, 0, (size_t)NSEQ * NSEQ);
  } else {
    for (int b = 0; b < BATCH; ++b) {
      gemm1_256<<<dim3(16, 16, 1), 512, 131072, stream>>>(
          Qbf, Kbf, Sbuf, Rsum, b, 0);
      gemm2_256<<<dim3(4, 16, 1), 512, 131072, stream>>>(
          Sbuf, Ktb, Rsum, out, b, 0);
    }
  }
}

// Round 5
// 670.527 us; speedup vs baseline: 6.0306x; 1.1552x over previous
//
#include <hip/hip_runtime.h>
#include <hip/hip_bf16.h>
#include <stdint.h>

#define DIMD 1024
#define NSEQ 4096
#define BATCH 8
#define LN_EPS 1e-5f

typedef __attribute__((ext_vector_type(8))) short bf16x8;
typedef __attribute__((ext_vector_type(4))) float f32x4;

__device__ __forceinline__ ushort f2bf(float f) {
  union { __hip_bfloat16 h; ushort u; } cv;
  cv.h = __float2bfloat16(f);
  return cv.u;
}

__device__ __forceinline__ void gload16(const void* g, void* l) {
  __builtin_amdgcn_global_load_lds(
      (const __attribute__((address_space(1))) uint32_t*)g,
      (__attribute__((address_space(3))) uint32_t*)l, 16, 0, 0);
}

// barriers for the 8-phase schedule (verified in round 3 — do not touch).
#define MIDBAR()   asm volatile("s_barrier" ::: "memory")
#define ENDBAR()   asm volatile("s_waitcnt lgkmcnt(0)\n\ts_barrier" ::: "memory")
#define ENDBARV4() asm volatile("s_waitcnt vmcnt(4) lgkmcnt(0)\n\ts_barrier" ::: "memory")
#define ENDBARV0() asm volatile("s_waitcnt vmcnt(0) lgkmcnt(0)\n\ts_barrier" ::: "memory")

// LDS XOR swizzle (involution): XOR 16B-slot index (byte bits 4-5) with row
// bits 1-2 (rows are 64B). Read-side lanes (l15,lg) then cover all 8
// bank-quads exactly twice -> 2-way = free (m136). Inverse applied to the
// global source of global_load_lds (linear LDS dest), per rule 21.
__device__ __forceinline__ int swz64(int byte) {
  return byte ^ (((byte >> 7) & 3) << 4);
}

// ---------------- LayerNorm (fp32 in -> bf16 out, scale folded) -------------
__global__ __launch_bounds__(256) void ln_bf16_kernel(
    const float* __restrict__ x, const float* __restrict__ gamma,
    const float* __restrict__ beta, ushort* __restrict__ y, float scale)
{
  const int lane = threadIdx.x & 63;
  const int wv   = threadIdx.x >> 6;
  const size_t row = (size_t)blockIdx.x * 4 + wv;
  const float* xr = x + row * DIMD;

  float4 v[4];
#pragma unroll
  for (int c = 0; c < 4; ++c)
    v[c] = *(const float4*)(xr + c * 256 + lane * 4);

  float s = 0.f;
#pragma unroll
  for (int c = 0; c < 4; ++c) s += v[c].x + v[c].y + v[c].z + v[c].w;
#pragma unroll
  for (int m = 32; m >= 1; m >>= 1) s += __shfl_xor(s, m, 64);
  const float mean = s * (1.0f / DIMD);

  float vs = 0.f;
#pragma unroll
  for (int c = 0; c < 4; ++c) {
    float a0 = v[c].x - mean, a1 = v[c].y - mean;
    float a2 = v[c].z - mean, a3 = v[c].w - mean;
    vs += a0 * a0 + a1 * a1 + a2 * a2 + a3 * a3;
  }
#pragma unroll
  for (int m = 32; m >= 1; m >>= 1) vs += __shfl_xor(vs, m, 64);
  const float rstd = rsqrtf(vs * (1.0f / DIMD) + LN_EPS);

  ushort* yr = y + row * DIMD;
#pragma unroll
  for (int c = 0; c < 4; ++c) {
    const int d = c * 256 + lane * 4;
    float4 g  = *(const float4*)(gamma + d);
    float4 bb = *(const float4*)(beta + d);
    ushort4 o;
    o.x = f2bf(((v[c].x - mean) * rstd * g.x + bb.x) * scale);
    o.y = f2bf(((v[c].y - mean) * rstd * g.y + bb.y) * scale);
    o.z = f2bf(((v[c].z - mean) * rstd * g.z + bb.z) * scale);
    o.w = f2bf(((v[c].w - mean) * rstd * g.w + bb.w) * scale);
    *(ushort4*)(yr + d) = o;
  }
}

// ---------------- bf16 transpose: [b][n][d] -> [b][d][n] --------------------
__global__ __launch_bounds__(256) void transpose_kernel(
    const ushort* __restrict__ src, ushort* __restrict__ dst)
{
  __shared__ ushort tile[64][72];
  const int t   = threadIdx.x;
  const int bid = blockIdx.x;
  const int b   = bid >> 10;
  const int rem = bid & 1023;
  const int n0  = (rem >> 4) << 6;
  const int d0  = (rem & 15) << 6;
  const ushort* sb = src + ((size_t)b * NSEQ) * DIMD;
  ushort* db       = dst + ((size_t)b * DIMD) * NSEQ;

#pragma unroll
  for (int k = 0; k < 2; ++k) {
    int c = t + 256 * k;
    int r = c >> 3, scol = (c & 7) * 8;
    *(uint4*)&tile[r][scol] =
        *(const uint4*)(sb + (size_t)(n0 + r) * DIMD + d0 + scol);
  }
  __syncthreads();
#pragma unroll
  for (int k = 0; k < 2; ++k) {
    int c = t + 256 * k;
    int dr = c >> 3, ns = (c & 7) * 8;
    union { ushort u[8]; uint4 q; } tv;
#pragma unroll
    for (int i = 0; i < 8; ++i) tv.u[i] = tile[ns + i][dr];
    *(uint4*)(db + (size_t)(d0 + dr) * NSEQ + n0 + ns) = tv.q;
  }
}

// ================== 256x256 8-phase GEMM core ===============================
// 512 thr = 8 waves. "A" operand = the 8-frag (C-row) operand, "B" = the
// 4-frag cached (C-col) operand. BK=64 as 2 k-half chunks of [256 rows][32
// cols] bf16 (16 KB), XOR-swizzled (swz64) on both sides.
// LDS: 2 dbuf x 4 chunks = 128 KB. Counted vmcnt(4) at phases 1 & 3 only.

__device__ __forceinline__ void stage_chunk(const ushort* __restrict__ g,
                                            int ld, char* l, int tid) {
  // LDS dest linear (tid*16, +8192); global source = inverse-swizzled element.
  const int o0 = tid * 16;
  const int o1 = o0 + 8192;
  const int s0 = swz64(o0);
  const int s1 = swz64(o1);
  gload16(g + (size_t)(s0 >> 6) * ld + ((s0 & 63) >> 1), l + o0);
  gload16(g + (size_t)(s1 >> 6) * ld + ((s1 & 63) >> 1), l + o1);
}

__device__ __forceinline__ bf16x8 ldsw_read(const char* base, int row, int lg) {
  return *(const bf16x8*)(base + swz64(row * 64 + lg * 16));
}

__device__ __forceinline__ void read_af(const char* Ac, int wm, int mh,
                                        int l15, int lg, bf16x8 (&af)[4]) {
#pragma unroll
  for (int m = 0; m < 4; ++m)
    af[m] = ldsw_read(Ac, wm * 128 + (mh * 4 + m) * 16 + l15, lg);
}
__device__ __forceinline__ void read_bf(const char* Bc, int wn,
                                        int l15, int lg, bf16x8 (&bf)[4]) {
#pragma unroll
  for (int n = 0; n < 4; ++n)
    bf[n] = ldsw_read(Bc, wn * 64 + n * 16 + l15, lg);
}

__device__ __forceinline__ void gemm_core_256(
    const ushort* __restrict__ Ab, const ushort* __restrict__ Bb,
    int lda, int ldb, int NT, char* smem, f32x4 (&acc)[8][4],
    int tid, int wm, int wn, int l15, int lg)
{
  // prologue: tile 0 -> buf0, issue order [Ak0, Bk0, Ak1, Bk1]
  stage_chunk(Ab,      lda, smem + 0,     tid);
  stage_chunk(Bb,      ldb, smem + 32768, tid);
  stage_chunk(Ab + 32, lda, smem + 16384, tid);
  stage_chunk(Bb + 32, ldb, smem + 49152, tid);
  ENDBARV4();  // completes Ak0,Bk0; keeps Ak1,Bk1 in flight

  for (int kt = 0; kt < NT; ++kt) {
    char* cb = smem + (kt & 1) * 65536;
    char* nbuf = smem + (((kt & 1) ^ 1) * 65536);
    const ushort* An = Ab + (size_t)(kt + 1) * 64;
    const ushort* Bn = Bb + (size_t)(kt + 1) * 64;
    const bool pf = (kt + 1 < NT);
    const char* A0 = cb;
    const char* A1 = cb + 16384;
    const char* B0 = cb + 32768;
    const char* B1 = cb + 49152;
    bf16x8 af[4], bf[4];

    // ---- phase 0: kh0, a-frags 0-3 + b-frags, prefetch next.Ak0 ----
    read_af(A0, wm, 0, l15, lg, af);
    read_bf(B0, wn, l15, lg, bf);
    if (pf) stage_chunk(An, lda, nbuf + 0, tid);
    MIDBAR();
    __builtin_amdgcn_s_setprio(1);
#pragma unroll
    for (int m = 0; m < 4; ++m)
#pragma unroll
      for (int n = 0; n < 4; ++n)
        acc[m][n] = __builtin_amdgcn_mfma_f32_16x16x32_bf16(af[m], bf[n], acc[m][n], 0, 0, 0);
    __builtin_amdgcn_s_setprio(0);
    ENDBAR();

    // ---- phase 1: kh0, a-frags 4-7 (B cached), prefetch next.Bk0 ----
    read_af(A0, wm, 1, l15, lg, af);
    if (pf) stage_chunk(Bn, ldb, nbuf + 32768, tid);
    MIDBAR();
    __builtin_amdgcn_s_setprio(1);
#pragma unroll
    for (int m = 0; m < 4; ++m)
#pragma unroll
      for (int n = 0; n < 4; ++n)
        acc[4 + m][n] = __builtin_amdgcn_mfma_f32_16x16x32_bf16(af[m], bf[n], acc[4 + m][n], 0, 0, 0);
    __builtin_amdgcn_s_setprio(0);
    if (pf) { ENDBARV4(); } else { ENDBARV0(); }

    // ---- phase 2: kh1, a-frags 0-3 + b-frags, prefetch next.Ak1 ----
    read_af(A1, wm, 0, l15, lg, af);
    read_bf(B1, wn, l15, lg, bf);
    if (pf) stage_chunk(An + 32, lda, nbuf + 16384, tid);
    MIDBAR();
    __builtin_amdgcn_s_setprio(1);
#pragma unroll
    for (int m = 0; m < 4; ++m)
#pragma unroll
      for (int n = 0; n < 4; ++n)
        acc[m][n] = __builtin_amdgcn_mfma_f32_16x16x32_bf16(af[m], bf[n], acc[m][n], 0, 0, 0);
    __builtin_amdgcn_s_setprio(0);
    ENDBAR();

    // ---- phase 3: kh1, a-frags 4-7, prefetch next.Bk1 ----
    read_af(A1, wm, 1, l15, lg, af);
    if (pf) stage_chunk(Bn + 32, ldb, nbuf + 49152, tid);
    MIDBAR();
    __builtin_amdgcn_s_setprio(1);
#pragma unroll
    for (int m = 0; m < 4; ++m)
#pragma unroll
      for (int n = 0; n < 4; ++n)
        acc[4 + m][n] = __builtin_amdgcn_mfma_f32_16x16x32_bf16(af[m], bf[n], acc[4 + m][n], 0, 0, 0);
    __builtin_amdgcn_s_setprio(0);
    if (pf) { ENDBARV4(); } else { ENDBAR(); }
  }
}

// GEMM1: S = exp(Q.K^T) stored [v][t] row-major; row-sums via atomics.
// OPERAND-SWAPPED: af = K-frags (C rows = t), bf = Q-frags (C cols = v) so
// each lane owns 4 contiguous t -> 8B vector stores along S's fast dim.
__global__ __launch_bounds__(512, 2) void gemm1_256(
    const ushort* __restrict__ Q, const ushort* __restrict__ K,
    ushort* __restrict__ S, float* __restrict__ Rsum,
    int b0, size_t s_stride)
{
  extern __shared__ char smem[];
  const int tid  = threadIdx.x;
  const int lane = tid & 63;
  const int wave = tid >> 6;
  const int wm = wave >> 2, wn = wave & 3;
  const int l15 = lane & 15, lg = lane >> 4;

  int bx, by, bzc;
  if (gridDim.z == BATCH) {
    // batch-per-XCD: hw linear id % 8 selects XCD; pin batch to XCD, sweep bx
    // fastest within (Q-panel L2 reuse).
    const int hw = blockIdx.x + (blockIdx.y << 4) + (blockIdx.z << 8);
    bzc = hw & 7;
    const int inner = hw >> 3;
    bx = inner & 15; by = (inner >> 4) & 15;
  } else {
    bx = blockIdx.x; by = blockIdx.y; bzc = 0;
  }

  const int bz   = b0 + bzc;
  const int row0 = by * 256, col0 = bx * 256;   // row0 = v (Q), col0 = t (K)
  const ushort* Qb = Q + (size_t)bz * NSEQ * DIMD + (size_t)row0 * DIMD;
  const ushort* Kb = K + (size_t)bz * NSEQ * DIMD + (size_t)col0 * DIMD;

  f32x4 acc[8][4];
#pragma unroll
  for (int m = 0; m < 8; ++m)
#pragma unroll
    for (int n = 0; n < 4; ++n) acc[m][n] = 0.0f;

  // swapped: A-role (8 frags, C-rows=t) = K tile; B-role (4 frags, C-cols=v) = Q tile
  gemm_core_256(Kb, Qb, DIMD, DIMD, DIMD / 64, smem, acc, tid, wm, wn, l15, lg);

  // epilogue: acc[ti][vi][i] = S-hat[t = col0+wm*128+ti*16+lg*4+i][v = row0+wn*64+vi*16+l15]
  ushort* Sb = S + (size_t)bzc * s_stride;
  float*  Rs = Rsum + (size_t)bz * NSEQ;
  float vsum[4] = {0.f, 0.f, 0.f, 0.f};
#pragma unroll
  for (int ti = 0; ti < 8; ++ti) {
#pragma unroll
    for (int vi = 0; vi < 4; ++vi) {
      const int v = row0 + wn * 64 + vi * 16 + l15;
      const int t = col0 + wm * 128 + ti * 16 + lg * 4;
      float p0 = __expf(acc[ti][vi][0]);
      float p1 = __expf(acc[ti][vi][1]);
      float p2 = __expf(acc[ti][vi][2]);
      float p3 = __expf(acc[ti][vi][3]);
      vsum[vi] += (p0 + p1) + (p2 + p3);
      unsigned long long pk =
          (unsigned long long)f2bf(p0)        |
          ((unsigned long long)f2bf(p1) << 16) |
          ((unsigned long long)f2bf(p2) << 32) |
          ((unsigned long long)f2bf(p3) << 48);
      *(unsigned long long*)(Sb + (size_t)v * NSEQ + t) = pk;
    }
  }
#pragma unroll
  for (int vi = 0; vi < 4; ++vi) {
    float s = vsum[vi];
    s += __shfl_xor(s, 16, 64);
    s += __shfl_xor(s, 32, 64);
    if (lg == 0)
      atomicAdd(Rs + row0 + wn * 64 + vi * 16 + l15, s);
  }
}

// GEMM2: O = (S.V)/Rsum stored [v][d] row-major. OPERAND-SWAPPED:
// af = Vt-frags (C rows = d), bf = S-frags (C cols = v) -> 16B f32x4 stores.
__global__ __launch_bounds__(512, 2) void gemm2_256(
    const ushort* __restrict__ S, const ushort* __restrict__ Kt,
    const float* __restrict__ Rsum, float* __restrict__ Out,
    int b0, size_t s_stride)
{
  extern __shared__ char smem[];
  const int tid  = threadIdx.x;
  const int lane = tid & 63;
  const int wave = tid >> 6;
  const int wm = wave >> 2, wn = wave & 3;
  const int l15 = lane & 15, lg = lane >> 4;

  int bx, by, bzc;
  if (gridDim.z == BATCH) {
    const int hw = blockIdx.x + (blockIdx.y << 2) + (blockIdx.z << 6);
    bzc = hw & 7;
    const int inner = hw >> 3;
    bx = inner & 3; by = inner >> 2;
  } else {
    bx = blockIdx.x; by = blockIdx.y; bzc = 0;
  }

  const int bz   = b0 + bzc;
  const int row0 = by * 256;   // v rows
  const int col0 = bx * 256;   // d cols
  const ushort* Sb2 = S  + (size_t)bzc * s_stride + (size_t)row0 * NSEQ;
  const ushort* Vtb = Kt + ((size_t)bz * DIMD + col0) * NSEQ;

  f32x4 acc[8][4];
#pragma unroll
  for (int m = 0; m < 8; ++m)
#pragma unroll
    for (int n = 0; n < 4; ++n) acc[m][n] = 0.0f;

  // swapped: A-role (8 frags, C-rows=d) = Vt tile; B-role (C-cols=v) = S tile
  gemm_core_256(Vtb, Sb2, NSEQ, NSEQ, NSEQ / 64, smem, acc, tid, wm, wn, l15, lg);

  // epilogue: acc[di][vi][i] = O[v = row0+wn*64+vi*16+l15][d = col0+wm*128+di*16+lg*4+i]
  const float* Rs = Rsum + (size_t)bz * NSEQ;
  float* Ob = Out + (size_t)bz * NSEQ * DIMD;
  float inv[4];
#pragma unroll
  for (int vi = 0; vi < 4; ++vi)
    inv[vi] = 1.0f / Rs[row0 + wn * 64 + vi * 16 + l15];
#pragma unroll
  for (int di = 0; di < 8; ++di) {
#pragma unroll
    for (int vi = 0; vi < 4; ++vi) {
      const int v = row0 + wn * 64 + vi * 16 + l15;
      const int d = col0 + wm * 128 + di * 16 + lg * 4;
      f32x4 o = acc[di][vi] * inv[vi];
      __builtin_nontemporal_store(
          o, (f32x4*)(Ob + (size_t)v * DIMD + d));
    }
  }
}

extern "C" void kernel_launch(void* const* d_in, const int* in_sizes, int n_in,
                              void* d_out, int out_size, void* d_ws, size_t ws_size,
                              hipStream_t stream) {
  const float* vis = (const float*)d_in[0];
  const float* txt = (const float*)d_in[1];
  const float* gv  = (const float*)d_in[2];
  const float* bv  = (const float*)d_in[3];
  const float* gt  = (const float*)d_in[4];
  const float* bt  = (const float*)d_in[5];
  float* out = (float*)d_out;

  const size_t tokens = (size_t)BATCH * NSEQ * DIMD;      // 33,554,432 elems
  ushort* Qbf = (ushort*)d_ws;                            // 64 MiB
  ushort* Kbf = Qbf + tokens;                             // 64 MiB
  ushort* Ktb = Kbf + tokens;                             // 64 MiB
  char*   wsb = (char*)d_ws;
  float*  Rsum = (float*)(wsb + 201326592);               // @192 MiB
  ushort* Sbuf = (ushort*)(wsb + 201457664);              // S region

  const size_t S_FULL = (size_t)BATCH * NSEQ * NSEQ * 2;  // 256 MiB
  const size_t NEED_FULL = 201457664 + S_FULL;

  ln_bf16_kernel<<<BATCH * NSEQ / 4, 256, 0, stream>>>(vis, gv, bv, Qbf, 0.03125f);
  ln_bf16_kernel<<<BATCH * NSEQ / 4, 256, 0, stream>>>(txt, gt, bt, Kbf, 1.0f);
  transpose_kernel<<<BATCH * (NSEQ / 64) * (DIMD / 64), 256, 0, stream>>>(Kbf, Ktb);

  hipFuncSetAttribute((const void*)gemm1_256,
                      hipFuncAttributeMaxDynamicSharedMemorySize, 131072);
  hipFuncSetAttribute((const void*)gemm2_256,
                      hipFuncAttributeMaxDynamicSharedMemorySize, 131072);

  hipMemsetAsync(Rsum, 0, (size_t)BATCH * NSEQ * sizeof(float), stream);

  if (ws_size >= NEED_FULL) {
    gemm1_256<<<dim3(16, 16, BATCH), 512, 131072, stream>>>(
        Qbf, Kbf, Sbuf, Rsum, 0, (size_t)NSEQ * NSEQ);
    gemm2_256<<<dim3(4, 16, BATCH), 512, 131072, stream>>>(
        Sbuf, Ktb, Rsum, out, 0, (size_t)NSEQ * NSEQ);
  } else {
    for (int b = 0; b < BATCH; ++b) {
      gemm1_256<<<dim3(16, 16, 1), 512, 131072, stream>>>(
          Qbf, Kbf, Sbuf, Rsum, b, 0);
      gemm2_256<<<dim3(4, 16, 1), 512, 131072, stream>>>(
          Sbuf, Ktb, Rsum, out, b, 0);
    }
  }
}